// Round 16
// baseline (144.388 us; speedup 1.0000x reference)
//
#include <hip/hip_runtime.h>
#include <hip/hip_bf16.h>

typedef _Float16 half8 __attribute__((ext_vector_type(8)));
typedef _Float16 f16x8 __attribute__((ext_vector_type(8)));
typedef __bf16 bf16x2v __attribute__((ext_vector_type(2)));
typedef __bf16 bf16x8 __attribute__((ext_vector_type(8)));
typedef float f32x16 __attribute__((ext_vector_type(16)));
typedef unsigned uint2v __attribute__((ext_vector_type(2)));

#define NPIX 16384      // H*W
#define NPOOL 4096      // pooled N
#define BN 32768        // B*N
#define KSPLIT 8
#define CHUNK 512       // NPOOL/KSPLIT
#define NSTEP 4         // CHUNK/128 (128 keys per barrier frame)
#define LOG2E 1.44269504088896340736f

__device__ inline f32x16 mfma16(half8 a, half8 b, f32x16 c) {
  return __builtin_amdgcn_mfma_f32_32x32x16_f16(a, b, c, 0, 0, 0);
}
__device__ inline f32x16 mfma16b(bf16x8 a, bf16x8 b, f32x16 c) {
  return __builtin_amdgcn_mfma_f32_32x32x16_bf16(a, b, c, 0, 0, 0);
}
__device__ inline float fast_exp2(float x) {
#if __has_builtin(__builtin_amdgcn_exp2f)
  return __builtin_amdgcn_exp2f(x);      // raw v_exp_f32 (1 inst, <=1 ulp)
#else
  return exp2f(x);
#endif
}

// ---- K1 (fused prep): theta f16 [BN][8]*log2e; phiT f16 [b][M][8]; gT bf16 [b][64][M]
__global__ __launch_bounds__(256) void prep_kernel(
    const float* __restrict__ x,
    const float* __restrict__ w_theta, const float* __restrict__ b_theta,
    const float* __restrict__ w_phi, const float* __restrict__ b_phi,
    const float* __restrict__ w_g, const float* __restrict__ b_g,
    _Float16* __restrict__ qf, _Float16* __restrict__ phiT,
    __bf16* __restrict__ gT) {
  __shared__ float xs[64][256];
  int bid = blockIdx.x;
  int oh = bid & 1;
  int pr = (bid >> 1) & 63;
  int b  = bid >> 7;
  int t = threadIdx.x;

  const float* xb = x + (size_t)b * 64 * NPIX + pr * 256;
#pragma unroll 8
  for (int c = 0; c < 64; c++) xs[c][t] = xb[(size_t)c * NPIX + t];
  __syncthreads();

  if (oh == 0) {
    float acc[8];
#pragma unroll
    for (int j = 0; j < 8; j++) acc[j] = b_theta[j];
#pragma unroll 4
    for (int c = 0; c < 64; c++) {
      float xv = xs[c][t];
#pragma unroll
      for (int j = 0; j < 8; j++) acc[j] += xv * w_theta[j * 64 + c];
    }
    half8 h;
#pragma unroll
    for (int j = 0; j < 8; j++) h[j] = (_Float16)(acc[j] * LOG2E);
    *(half8*)(qf + ((size_t)b * NPIX + pr * 256 + t) * 8) = h;
  }

  int pos = t & 63;
  int ocg = t >> 6;
  int oc0 = oh * 36 + ocg * 9;
  const float* wrow[9];
  float a0[9], a1[9], a2[9], a3[9];
#pragma unroll
  for (int j = 0; j < 9; j++) {
    int oc = oc0 + j;
    float bv;
    if (oc < 64) { wrow[j] = w_g + oc * 64; bv = b_g[oc]; }
    else         { wrow[j] = w_phi + (oc - 64) * 64; bv = b_phi[oc - 64]; }
    a0[j] = bv; a1[j] = bv; a2[j] = bv; a3[j] = bv;
  }
#pragma unroll 4
  for (int c = 0; c < 64; c++) {
    float2 lo = *(const float2*)&xs[c][2 * pos];
    float2 hi = *(const float2*)&xs[c][128 + 2 * pos];
#pragma unroll
    for (int j = 0; j < 9; j++) {
      float wv = wrow[j][c];
      a0[j] += wv * lo.x;
      a1[j] += wv * lo.y;
      a2[j] += wv * hi.x;
      a3[j] += wv * hi.y;
    }
  }
  int m = pr * 64 + pos;
#pragma unroll
  for (int j = 0; j < 9; j++) {
    int oc = oc0 + j;
    float v = fmaxf(fmaxf(a0[j], a1[j]), fmaxf(a2[j], a3[j]));
    if (oc < 64) gT[((size_t)b * 64 + oc) * NPOOL + m] = (__bf16)v;
    else         phiT[((size_t)b * NPOOL + m) * 8 + (oc - 64)] = (_Float16)v;
  }
}

// ---- K2: flash attention; 64 queries/wave (2 MFMA col-groups share LDS reads) ----
// grid = b(2) x qt(64) x kc(8) = 1024 blocks; 4 waves x 64 queries = 256 q/block
__global__ __launch_bounds__(256, 3) void attn_kernel(
    const _Float16* __restrict__ qf, const _Float16* __restrict__ phiT,
    const __bf16* __restrict__ gT,
    float* __restrict__ part_l, _Float16* __restrict__ part_o) {
  __shared__ __bf16 lds_g[2][128 * 64];  // double buffer, 16 KB each (128 keys)
  int bx = blockIdx.x;
  int kc = bx & (KSPLIT - 1);
  int qt = (bx >> 3) & 63;
  int b  = bx >> 9;
  int tid = threadIdx.x;
  int lane = tid & 63;
  int w = tid >> 6;
  int q = lane & 31, hi = lane >> 5;
  int qg0 = qt * 256 + w * 64;
  size_t qrowA = (size_t)b * NPIX + qg0 + q;
  size_t qrowB = qrowA + 32;

  half8 qfragA = {0, 0, 0, 0, 0, 0, 0, 0}, qfragB = qfragA;
  if (!hi) {
    qfragA = *(const half8*)(qf + qrowA * 8);
    qfragB = *(const half8*)(qf + qrowB * 8);
  }

  f32x16 oaccA0, oaccA1, oaccB0, oaccB1;
#pragma unroll
  for (int i = 0; i < 16; i++) {
    oaccA0[i] = 0.f; oaccA1[i] = 0.f; oaccB0[i] = 0.f; oaccB1[i] = 0.f;
  }
  float lsumA = 0.f, lsumB = 0.f;

  int kb0 = kc * CHUNK;

  // gl_lds staging: linear LDS dest (base + lane*16), inverse-swizzled source.
  const __bf16* gbase0;
  const __bf16* gbase1;
  {
    int c0 = (w * 2 + 0) * 8 + (lane >> 3);
    int c1 = (w * 2 + 1) * 8 + (lane >> 3);
    int s  = (lane & 7) ^ (lane >> 3);
    gbase0 = gT + ((size_t)b * 64 + c0) * NPOOL + 8 * s;
    gbase1 = gT + ((size_t)b * 64 + c1) * NPOOL + 8 * s;
  }
#define STAGE(buf, kb)                                                        \
  do {                                                                        \
    __builtin_amdgcn_global_load_lds(                                         \
        (const __attribute__((address_space(1))) void*)(gbase0 + (kb)),       \
        (__attribute__((address_space(3))) void*)((char*)&lds_g[buf][0] +     \
                                                  (w * 2 + 0) * 1024),        \
        16, 0, 0);                                                            \
    __builtin_amdgcn_global_load_lds(                                         \
        (const __attribute__((address_space(1))) void*)(gbase1 + (kb)),       \
        (__attribute__((address_space(3))) void*)((char*)&lds_g[buf][0] +     \
                                                  (w * 2 + 1) * 1024),        \
        16, 0, 0);                                                            \
    __builtin_amdgcn_global_load_lds(                                         \
        (const __attribute__((address_space(1))) void*)(gbase0 + (kb) + 64),  \
        (__attribute__((address_space(3))) void*)((char*)&lds_g[buf][0] +     \
                                                  8192 + (w * 2 + 0) * 1024), \
        16, 0, 0);                                                            \
    __builtin_amdgcn_global_load_lds(                                         \
        (const __attribute__((address_space(1))) void*)(gbase1 + (kb) + 64),  \
        (__attribute__((address_space(3))) void*)((char*)&lds_g[buf][0] +     \
                                                  8192 + (w * 2 + 1) * 1024), \
        16, 0, 0);                                                            \
  } while (0)

  STAGE(0, kb0);
  __syncthreads();                       // buf0 visible
  int cur = 0;

#pragma unroll 1
  for (int step = 0; step < NSTEP; ++step) {
    int kb = kb0 + step * 128;
    if (step + 1 < NSTEP) STAGE(cur ^ 1, kb + 128);  // prefetch next 128 keys
#pragma unroll
    for (int kk = 0; kk < 2; ++kk) {
      int kbb = kb + kk * 64;
      half8 aphi0 = {0, 0, 0, 0, 0, 0, 0, 0}, aphi1 = aphi0;
      if (!hi) {
        aphi0 = *(const half8*)(phiT + ((size_t)b * NPOOL + kbb + q) * 8);
        aphi1 = *(const half8*)(phiT + ((size_t)b * NPOOL + kbb + 32 + q) * 8);
      }
      const __bf16* ldsb = &lds_g[cur][kk * 4096];
#pragma unroll
      for (int sub = 0; sub < 2; ++sub) {
        half8 aphi = sub ? aphi1 : aphi0;
        f32x16 s0, s1;
#pragma unroll
        for (int i = 0; i < 16; i++) { s0[i] = 0.f; s1[i] = 0.f; }
        s0 = mfma16(aphi, qfragA, s0);   // scores: both groups share aphi
        s1 = mfma16(aphi, qfragB, s1);
        unsigned uA[8], uB[8];
        {
          float p[16];
#pragma unroll
          for (int i = 0; i < 16; i++) p[i] = fast_exp2(s0[i]);
          lsumA += (((p[0] + p[1]) + (p[2] + p[3])) + ((p[4] + p[5]) + (p[6] + p[7]))) +
                   (((p[8] + p[9]) + (p[10] + p[11])) + ((p[12] + p[13]) + (p[14] + p[15])));
#pragma unroll
          for (int h = 0; h < 2; ++h) {
            bf16x2v t0 = {(__bf16)p[h * 8 + 0], (__bf16)p[h * 8 + 1]};
            bf16x2v t1 = {(__bf16)p[h * 8 + 2], (__bf16)p[h * 8 + 3]};
            bf16x2v t2 = {(__bf16)p[h * 8 + 4], (__bf16)p[h * 8 + 5]};
            bf16x2v t3 = {(__bf16)p[h * 8 + 6], (__bf16)p[h * 8 + 7]};
            uA[h * 4 + 0] = __builtin_bit_cast(unsigned, t0);
            uA[h * 4 + 1] = __builtin_bit_cast(unsigned, t1);
            uA[h * 4 + 2] = __builtin_bit_cast(unsigned, t2);
            uA[h * 4 + 3] = __builtin_bit_cast(unsigned, t3);
          }
        }
        {
          float p[16];
#pragma unroll
          for (int i = 0; i < 16; i++) p[i] = fast_exp2(s1[i]);
          lsumB += (((p[0] + p[1]) + (p[2] + p[3])) + ((p[4] + p[5]) + (p[6] + p[7]))) +
                   (((p[8] + p[9]) + (p[10] + p[11])) + ((p[12] + p[13]) + (p[14] + p[15])));
#pragma unroll
          for (int h = 0; h < 2; ++h) {
            bf16x2v t0 = {(__bf16)p[h * 8 + 0], (__bf16)p[h * 8 + 1]};
            bf16x2v t1 = {(__bf16)p[h * 8 + 2], (__bf16)p[h * 8 + 3]};
            bf16x2v t2 = {(__bf16)p[h * 8 + 4], (__bf16)p[h * 8 + 5]};
            bf16x2v t3 = {(__bf16)p[h * 8 + 6], (__bf16)p[h * 8 + 7]};
            uB[h * 4 + 0] = __builtin_bit_cast(unsigned, t0);
            uB[h * 4 + 1] = __builtin_bit_cast(unsigned, t1);
            uB[h * 4 + 2] = __builtin_bit_cast(unsigned, t2);
            uB[h * 4 + 3] = __builtin_bit_cast(unsigned, t3);
          }
        }
#pragma unroll
        for (int halfk = 0; halfk < 2; ++halfk) {
          union { unsigned u[4]; bf16x8 h; } pfA, pfB;
#if __has_builtin(__builtin_amdgcn_permlane32_swap)
          uint2v rA0 = __builtin_amdgcn_permlane32_swap(uA[halfk * 4 + 0], uA[halfk * 4 + 2], false, false);
          uint2v rA1 = __builtin_amdgcn_permlane32_swap(uA[halfk * 4 + 1], uA[halfk * 4 + 3], false, false);
          pfA.u[0] = rA0[0]; pfA.u[1] = rA1[0]; pfA.u[2] = rA0[1]; pfA.u[3] = rA1[1];
          uint2v rB0 = __builtin_amdgcn_permlane32_swap(uB[halfk * 4 + 0], uB[halfk * 4 + 2], false, false);
          uint2v rB1 = __builtin_amdgcn_permlane32_swap(uB[halfk * 4 + 1], uB[halfk * 4 + 3], false, false);
          pfB.u[0] = rB0[0]; pfB.u[1] = rB1[0]; pfB.u[2] = rB0[1]; pfB.u[3] = rB1[1];
#else
          unsigned xA0 = __shfl_xor(uA[halfk * 4 + 0], 32), xA1 = __shfl_xor(uA[halfk * 4 + 1], 32);
          unsigned xA2 = __shfl_xor(uA[halfk * 4 + 2], 32), xA3 = __shfl_xor(uA[halfk * 4 + 3], 32);
          pfA.u[0] = hi ? xA2 : uA[halfk * 4 + 0];
          pfA.u[1] = hi ? xA3 : uA[halfk * 4 + 1];
          pfA.u[2] = hi ? uA[halfk * 4 + 2] : xA0;
          pfA.u[3] = hi ? uA[halfk * 4 + 3] : xA1;
          unsigned xB0 = __shfl_xor(uB[halfk * 4 + 0], 32), xB1 = __shfl_xor(uB[halfk * 4 + 1], 32);
          unsigned xB2 = __shfl_xor(uB[halfk * 4 + 2], 32), xB3 = __shfl_xor(uB[halfk * 4 + 3], 32);
          pfB.u[0] = hi ? xB2 : uB[halfk * 4 + 0];
          pfB.u[1] = hi ? xB3 : uB[halfk * 4 + 1];
          pfB.u[2] = hi ? uB[halfk * 4 + 2] : xB0;
          pfB.u[3] = hi ? uB[halfk * 4 + 3] : xB1;
#endif
          int sread = sub * 4 + halfk * 2 + hi;
          __builtin_amdgcn_s_setprio(1);
#pragma unroll
          for (int ct = 0; ct < 2; ++ct) {
            int row = ct * 32 + q;
            bf16x8 ag = *(const bf16x8*)(ldsb + row * 64 +
                                         (((16 * sread) ^ ((row & 7) << 4)) >> 1));
            if (ct == 0) { oaccA0 = mfma16b(ag, pfA.h, oaccA0); oaccB0 = mfma16b(ag, pfB.h, oaccB0); }
            else         { oaccA1 = mfma16b(ag, pfA.h, oaccA1); oaccB1 = mfma16b(ag, pfB.h, oaccB1); }
          }
          __builtin_amdgcn_s_setprio(0);
        }
      }
    }
    if (step + 1 < NSTEP) { __syncthreads(); cur ^= 1; }  // uniform condition
  }
  // ---- epilogue: per group, chunk-total l + normalized f16 partial o ----
  lsumA += __shfl_xor(lsumA, 32);
  lsumB += __shfl_xor(lsumB, 32);
  float rlA = 1.0f / lsumA, rlB = 1.0f / lsumB;
  if (!hi) {
    part_l[(size_t)kc * BN + qrowA] = lsumA;
    part_l[(size_t)kc * BN + qrowB] = lsumB;
  }
  _Float16* poA = part_o + (((size_t)(kc * 2 + b) * NPIX) + qg0 + q) * 64;
  _Float16* poB = poA + (size_t)32 * 64;
#pragma unroll
  for (int ct = 0; ct < 2; ++ct) {
#pragma unroll
    for (int cg = 0; cg < 4; ++cg) {
      float a0 = (ct ? oaccA1[4 * cg + 0] : oaccA0[4 * cg + 0]) * rlA;
      float a1 = (ct ? oaccA1[4 * cg + 1] : oaccA0[4 * cg + 1]) * rlA;
      float a2 = (ct ? oaccA1[4 * cg + 2] : oaccA0[4 * cg + 2]) * rlA;
      float a3 = (ct ? oaccA1[4 * cg + 3] : oaccA0[4 * cg + 3]) * rlA;
      uint2v u;
      u[0] = __builtin_bit_cast(unsigned, __builtin_amdgcn_cvt_pkrtz(a0, a1));
      u[1] = __builtin_bit_cast(unsigned, __builtin_amdgcn_cvt_pkrtz(a2, a3));
      *(uint2v*)(poA + 32 * ct + 8 * cg + 4 * hi) = u;
      float b0 = (ct ? oaccB1[4 * cg + 0] : oaccB0[4 * cg + 0]) * rlB;
      float b1 = (ct ? oaccB1[4 * cg + 1] : oaccB0[4 * cg + 1]) * rlB;
      float b2 = (ct ? oaccB1[4 * cg + 2] : oaccB0[4 * cg + 2]) * rlB;
      float b3 = (ct ? oaccB1[4 * cg + 3] : oaccB0[4 * cg + 3]) * rlB;
      uint2v v;
      v[0] = __builtin_bit_cast(unsigned, __builtin_amdgcn_cvt_pkrtz(b0, b1));
      v[1] = __builtin_bit_cast(unsigned, __builtin_amdgcn_cvt_pkrtz(b2, b3));
      *(uint2v*)(poB + 32 * ct + 8 * cg + 4 * hi) = v;
    }
  }
}

// ---- K3: l-weighted combine + residual epilogue ----
__global__ __launch_bounds__(256) void reduce_kernel(
    const float* __restrict__ part_l, const _Float16* __restrict__ part_o,
    const float* __restrict__ x, const float* __restrict__ sig,
    float* __restrict__ out) {
  int t = threadIdx.x;
  int cg = t >> 6;                       // 0..3 -> channels cg*16..+15
  int qi = blockIdx.x * 64 + (t & 63);
  int b = qi >> 14, n = qi & (NPIX - 1);
  float lv[KSPLIT], L = 0.f;
#pragma unroll
  for (int kc = 0; kc < KSPLIT; kc++) {
    lv[kc] = part_l[(size_t)kc * BN + qi];
    L += lv[kc];
  }
  float o16[16];
#pragma unroll
  for (int j = 0; j < 16; j++) o16[j] = 0.f;
#pragma unroll
  for (int kc = 0; kc < KSPLIT; kc++) {
    const _Float16* po = part_o + (((size_t)(kc * 2 + b) * NPIX) + n) * 64 + cg * 16;
    f16x8 v0 = *(const f16x8*)po;
    f16x8 v1 = *(const f16x8*)(po + 8);
    float wv = lv[kc];
#pragma unroll
    for (int j = 0; j < 8; j++) {
      o16[j]     += wv * (float)v0[j];
      o16[8 + j] += wv * (float)v1[j];
    }
  }
  float scale = sig[0] / L;
#pragma unroll
  for (int j = 0; j < 16; j++) {
    int c = cg * 16 + j;
    size_t idx = ((size_t)b * 64 + c) * NPIX + n;
    out[idx] = x[idx] + scale * o16[j];
  }
}

extern "C" void kernel_launch(void* const* d_in, const int* in_sizes, int n_in,
                              void* d_out, int out_size, void* d_ws, size_t ws_size,
                              hipStream_t stream) {
  const float* x       = (const float*)d_in[0];
  const float* w_theta = (const float*)d_in[1];
  const float* b_theta = (const float*)d_in[2];
  const float* w_phi   = (const float*)d_in[3];
  const float* b_phi   = (const float*)d_in[4];
  const float* w_g     = (const float*)d_in[5];
  const float* b_g     = (const float*)d_in[6];
  const float* sigma   = (const float*)d_in[7];
  float* out = (float*)d_out;

  // Workspace layout (bytes):
  //   qf     @ 0        : BN*8*2              = 524288
  //   phiT   @ 524288   : 2*NPOOL*8*2         = 131072
  //   gT     @ 655360   : 2*64*NPOOL*2        = 1048576  (bf16)
  //   part_l @ 1703936  : KSPLIT*BN*4         = 1048576
  //   part_o @ 2752512  : KSPLIT*2*NPIX*64*2  = 33554432   (total ~36.3 MB)
  char* ws = (char*)d_ws;
  _Float16* qf     = (_Float16*)ws;
  _Float16* phiT   = (_Float16*)(ws + 524288);
  __bf16*   gT     = (__bf16*)(ws + 655360);
  float*    part_l = (float*)(ws + 1703936);
  _Float16* part_o = (_Float16*)(ws + 2752512);

  prep_kernel<<<256, 256, 0, stream>>>(x, w_theta, b_theta, w_phi, b_phi,
                                       w_g, b_g, qf, phiT, gT);
  attn_kernel<<<2 * 64 * KSPLIT, 256, 0, stream>>>(qf, phiT, gT,
                                                   part_l, part_o);
  reduce_kernel<<<512, 256, 0, stream>>>(part_l, part_o, x, sigma, out);
}

// Round 17
// 68.425 us; speedup vs baseline: 2.1102x; 2.1102x over previous
//
#include <hip/hip_runtime.h>
#include <hip/hip_bf16.h>

typedef _Float16 half8 __attribute__((ext_vector_type(8)));
typedef _Float16 f16x8 __attribute__((ext_vector_type(8)));
typedef __bf16 bf16x2v __attribute__((ext_vector_type(2)));
typedef __bf16 bf16x8 __attribute__((ext_vector_type(8)));
typedef float f32x16 __attribute__((ext_vector_type(16)));
typedef unsigned uint2v __attribute__((ext_vector_type(2)));

#define NPIX 16384      // H*W
#define NPOOL 4096      // pooled N
#define BN 32768        // B*N
#define KSPLIT 8
#define CHUNK 512       // NPOOL/KSPLIT
#define NSTEP 4         // CHUNK/128 (128 keys per barrier frame)
#define LOG2E 1.44269504088896340736f

__device__ inline f32x16 mfma16(half8 a, half8 b, f32x16 c) {
  return __builtin_amdgcn_mfma_f32_32x32x16_f16(a, b, c, 0, 0, 0);
}
__device__ inline f32x16 mfma16b(bf16x8 a, bf16x8 b, f32x16 c) {
  return __builtin_amdgcn_mfma_f32_32x32x16_bf16(a, b, c, 0, 0, 0);
}
__device__ inline float fast_exp2(float x) {
#if __has_builtin(__builtin_amdgcn_exp2f)
  return __builtin_amdgcn_exp2f(x);      // raw v_exp_f32 (1 inst, <=1 ulp)
#else
  return exp2f(x);
#endif
}

// ---- K1 (fused prep): theta f16 [BN][8]*log2e; phiT f16 [b][M][8]; gT bf16 [b][64][M]
__global__ __launch_bounds__(256) void prep_kernel(
    const float* __restrict__ x,
    const float* __restrict__ w_theta, const float* __restrict__ b_theta,
    const float* __restrict__ w_phi, const float* __restrict__ b_phi,
    const float* __restrict__ w_g, const float* __restrict__ b_g,
    _Float16* __restrict__ qf, _Float16* __restrict__ phiT,
    __bf16* __restrict__ gT) {
  __shared__ float xs[64][256];
  int bid = blockIdx.x;
  int oh = bid & 1;
  int pr = (bid >> 1) & 63;
  int b  = bid >> 7;
  int t = threadIdx.x;

  const float* xb = x + (size_t)b * 64 * NPIX + pr * 256;
#pragma unroll 8
  for (int c = 0; c < 64; c++) xs[c][t] = xb[(size_t)c * NPIX + t];
  __syncthreads();

  if (oh == 0) {
    float acc[8];
#pragma unroll
    for (int j = 0; j < 8; j++) acc[j] = b_theta[j];
#pragma unroll 4
    for (int c = 0; c < 64; c++) {
      float xv = xs[c][t];
#pragma unroll
      for (int j = 0; j < 8; j++) acc[j] += xv * w_theta[j * 64 + c];
    }
    half8 h;
#pragma unroll
    for (int j = 0; j < 8; j++) h[j] = (_Float16)(acc[j] * LOG2E);
    *(half8*)(qf + ((size_t)b * NPIX + pr * 256 + t) * 8) = h;
  }

  int pos = t & 63;
  int ocg = t >> 6;
  int oc0 = oh * 36 + ocg * 9;
  const float* wrow[9];
  float a0[9], a1[9], a2[9], a3[9];
#pragma unroll
  for (int j = 0; j < 9; j++) {
    int oc = oc0 + j;
    float bv;
    if (oc < 64) { wrow[j] = w_g + oc * 64; bv = b_g[oc]; }
    else         { wrow[j] = w_phi + (oc - 64) * 64; bv = b_phi[oc - 64]; }
    a0[j] = bv; a1[j] = bv; a2[j] = bv; a3[j] = bv;
  }
#pragma unroll 4
  for (int c = 0; c < 64; c++) {
    float2 lo = *(const float2*)&xs[c][2 * pos];
    float2 hi = *(const float2*)&xs[c][128 + 2 * pos];
#pragma unroll
    for (int j = 0; j < 9; j++) {
      float wv = wrow[j][c];
      a0[j] += wv * lo.x;
      a1[j] += wv * lo.y;
      a2[j] += wv * hi.x;
      a3[j] += wv * hi.y;
    }
  }
  int m = pr * 64 + pos;
#pragma unroll
  for (int j = 0; j < 9; j++) {
    int oc = oc0 + j;
    float v = fmaxf(fmaxf(a0[j], a1[j]), fmaxf(a2[j], a3[j]));
    if (oc < 64) gT[((size_t)b * 64 + oc) * NPOOL + m] = (__bf16)v;
    else         phiT[((size_t)b * NPOOL + m) * 8 + (oc - 64)] = (_Float16)v;
  }
}

// ---- K2: flash attention; 64 queries/wave (2 MFMA col-groups share LDS reads) ----
// grid = b(2) x qt(64) x kc(8) = 1024 blocks; 4 waves x 64 queries = 256 q/block
// launch_bounds(256,2): round-16's (256,3) squeezed unified VGPR+AGPR to ~170
// -> 84 arch VGPRs -> 317 MB scratch spill. 2 waves/EU budget (256) fits all.
__global__ __launch_bounds__(256, 2) void attn_kernel(
    const _Float16* __restrict__ qf, const _Float16* __restrict__ phiT,
    const __bf16* __restrict__ gT,
    float* __restrict__ part_l, _Float16* __restrict__ part_o) {
  __shared__ __bf16 lds_g[2][128 * 64];  // double buffer, 16 KB each (128 keys)
  int bx = blockIdx.x;
  int kc = bx & (KSPLIT - 1);
  int qt = (bx >> 3) & 63;
  int b  = bx >> 9;
  int tid = threadIdx.x;
  int lane = tid & 63;
  int w = tid >> 6;
  int q = lane & 31, hi = lane >> 5;
  int qg0 = qt * 256 + w * 64;
  size_t qrowA = (size_t)b * NPIX + qg0 + q;
  size_t qrowB = qrowA + 32;

  half8 qfragA = {0, 0, 0, 0, 0, 0, 0, 0}, qfragB = qfragA;
  if (!hi) {
    qfragA = *(const half8*)(qf + qrowA * 8);
    qfragB = *(const half8*)(qf + qrowB * 8);
  }

  f32x16 oaccA0, oaccA1, oaccB0, oaccB1;
#pragma unroll
  for (int i = 0; i < 16; i++) {
    oaccA0[i] = 0.f; oaccA1[i] = 0.f; oaccB0[i] = 0.f; oaccB1[i] = 0.f;
  }
  float lsumA = 0.f, lsumB = 0.f;

  int kb0 = kc * CHUNK;

  // gl_lds staging: linear LDS dest (base + lane*16), inverse-swizzled source.
  const __bf16* gbase0;
  const __bf16* gbase1;
  {
    int c0 = (w * 2 + 0) * 8 + (lane >> 3);
    int c1 = (w * 2 + 1) * 8 + (lane >> 3);
    int s  = (lane & 7) ^ (lane >> 3);
    gbase0 = gT + ((size_t)b * 64 + c0) * NPOOL + 8 * s;
    gbase1 = gT + ((size_t)b * 64 + c1) * NPOOL + 8 * s;
  }
#define STAGE(buf, kb)                                                        \
  do {                                                                        \
    __builtin_amdgcn_global_load_lds(                                         \
        (const __attribute__((address_space(1))) void*)(gbase0 + (kb)),       \
        (__attribute__((address_space(3))) void*)((char*)&lds_g[buf][0] +     \
                                                  (w * 2 + 0) * 1024),        \
        16, 0, 0);                                                            \
    __builtin_amdgcn_global_load_lds(                                         \
        (const __attribute__((address_space(1))) void*)(gbase1 + (kb)),       \
        (__attribute__((address_space(3))) void*)((char*)&lds_g[buf][0] +     \
                                                  (w * 2 + 1) * 1024),        \
        16, 0, 0);                                                            \
    __builtin_amdgcn_global_load_lds(                                         \
        (const __attribute__((address_space(1))) void*)(gbase0 + (kb) + 64),  \
        (__attribute__((address_space(3))) void*)((char*)&lds_g[buf][0] +     \
                                                  8192 + (w * 2 + 0) * 1024), \
        16, 0, 0);                                                            \
    __builtin_amdgcn_global_load_lds(                                         \
        (const __attribute__((address_space(1))) void*)(gbase1 + (kb) + 64),  \
        (__attribute__((address_space(3))) void*)((char*)&lds_g[buf][0] +     \
                                                  8192 + (w * 2 + 1) * 1024), \
        16, 0, 0);                                                            \
  } while (0)

  STAGE(0, kb0);
  __syncthreads();                       // buf0 visible
  int cur = 0;

#pragma unroll 1
  for (int step = 0; step < NSTEP; ++step) {
    int kb = kb0 + step * 128;
    if (step + 1 < NSTEP) STAGE(cur ^ 1, kb + 128);  // prefetch next 128 keys
#pragma unroll
    for (int kk = 0; kk < 2; ++kk) {
      int kbb = kb + kk * 64;
      half8 aphi0 = {0, 0, 0, 0, 0, 0, 0, 0}, aphi1 = aphi0;
      if (!hi) {
        aphi0 = *(const half8*)(phiT + ((size_t)b * NPOOL + kbb + q) * 8);
        aphi1 = *(const half8*)(phiT + ((size_t)b * NPOOL + kbb + 32 + q) * 8);
      }
      const __bf16* ldsb = &lds_g[cur][kk * 4096];
#pragma unroll
      for (int sub = 0; sub < 2; ++sub) {
        half8 aphi = sub ? aphi1 : aphi0;
        f32x16 s0, s1;
#pragma unroll
        for (int i = 0; i < 16; i++) { s0[i] = 0.f; s1[i] = 0.f; }
        s0 = mfma16(aphi, qfragA, s0);   // scores: both groups share aphi
        s1 = mfma16(aphi, qfragB, s1);
        unsigned uA[8], uB[8];
        {
          float p[16];
#pragma unroll
          for (int i = 0; i < 16; i++) p[i] = fast_exp2(s0[i]);
          lsumA += (((p[0] + p[1]) + (p[2] + p[3])) + ((p[4] + p[5]) + (p[6] + p[7]))) +
                   (((p[8] + p[9]) + (p[10] + p[11])) + ((p[12] + p[13]) + (p[14] + p[15])));
#pragma unroll
          for (int h = 0; h < 2; ++h) {
            bf16x2v t0 = {(__bf16)p[h * 8 + 0], (__bf16)p[h * 8 + 1]};
            bf16x2v t1 = {(__bf16)p[h * 8 + 2], (__bf16)p[h * 8 + 3]};
            bf16x2v t2 = {(__bf16)p[h * 8 + 4], (__bf16)p[h * 8 + 5]};
            bf16x2v t3 = {(__bf16)p[h * 8 + 6], (__bf16)p[h * 8 + 7]};
            uA[h * 4 + 0] = __builtin_bit_cast(unsigned, t0);
            uA[h * 4 + 1] = __builtin_bit_cast(unsigned, t1);
            uA[h * 4 + 2] = __builtin_bit_cast(unsigned, t2);
            uA[h * 4 + 3] = __builtin_bit_cast(unsigned, t3);
          }
        }
        {
          float p[16];
#pragma unroll
          for (int i = 0; i < 16; i++) p[i] = fast_exp2(s1[i]);
          lsumB += (((p[0] + p[1]) + (p[2] + p[3])) + ((p[4] + p[5]) + (p[6] + p[7]))) +
                   (((p[8] + p[9]) + (p[10] + p[11])) + ((p[12] + p[13]) + (p[14] + p[15])));
#pragma unroll
          for (int h = 0; h < 2; ++h) {
            bf16x2v t0 = {(__bf16)p[h * 8 + 0], (__bf16)p[h * 8 + 1]};
            bf16x2v t1 = {(__bf16)p[h * 8 + 2], (__bf16)p[h * 8 + 3]};
            bf16x2v t2 = {(__bf16)p[h * 8 + 4], (__bf16)p[h * 8 + 5]};
            bf16x2v t3 = {(__bf16)p[h * 8 + 6], (__bf16)p[h * 8 + 7]};
            uB[h * 4 + 0] = __builtin_bit_cast(unsigned, t0);
            uB[h * 4 + 1] = __builtin_bit_cast(unsigned, t1);
            uB[h * 4 + 2] = __builtin_bit_cast(unsigned, t2);
            uB[h * 4 + 3] = __builtin_bit_cast(unsigned, t3);
          }
        }
#pragma unroll
        for (int halfk = 0; halfk < 2; ++halfk) {
          union { unsigned u[4]; bf16x8 h; } pfA, pfB;
#if __has_builtin(__builtin_amdgcn_permlane32_swap)
          uint2v rA0 = __builtin_amdgcn_permlane32_swap(uA[halfk * 4 + 0], uA[halfk * 4 + 2], false, false);
          uint2v rA1 = __builtin_amdgcn_permlane32_swap(uA[halfk * 4 + 1], uA[halfk * 4 + 3], false, false);
          pfA.u[0] = rA0[0]; pfA.u[1] = rA1[0]; pfA.u[2] = rA0[1]; pfA.u[3] = rA1[1];
          uint2v rB0 = __builtin_amdgcn_permlane32_swap(uB[halfk * 4 + 0], uB[halfk * 4 + 2], false, false);
          uint2v rB1 = __builtin_amdgcn_permlane32_swap(uB[halfk * 4 + 1], uB[halfk * 4 + 3], false, false);
          pfB.u[0] = rB0[0]; pfB.u[1] = rB1[0]; pfB.u[2] = rB0[1]; pfB.u[3] = rB1[1];
#else
          unsigned xA0 = __shfl_xor(uA[halfk * 4 + 0], 32), xA1 = __shfl_xor(uA[halfk * 4 + 1], 32);
          unsigned xA2 = __shfl_xor(uA[halfk * 4 + 2], 32), xA3 = __shfl_xor(uA[halfk * 4 + 3], 32);
          pfA.u[0] = hi ? xA2 : uA[halfk * 4 + 0];
          pfA.u[1] = hi ? xA3 : uA[halfk * 4 + 1];
          pfA.u[2] = hi ? uA[halfk * 4 + 2] : xA0;
          pfA.u[3] = hi ? uA[halfk * 4 + 3] : xA1;
          unsigned xB0 = __shfl_xor(uB[halfk * 4 + 0], 32), xB1 = __shfl_xor(uB[halfk * 4 + 1], 32);
          unsigned xB2 = __shfl_xor(uB[halfk * 4 + 2], 32), xB3 = __shfl_xor(uB[halfk * 4 + 3], 32);
          pfB.u[0] = hi ? xB2 : uB[halfk * 4 + 0];
          pfB.u[1] = hi ? xB3 : uB[halfk * 4 + 1];
          pfB.u[2] = hi ? uB[halfk * 4 + 2] : xB0;
          pfB.u[3] = hi ? uB[halfk * 4 + 3] : xB1;
#endif
          int sread = sub * 4 + halfk * 2 + hi;
          __builtin_amdgcn_s_setprio(1);
#pragma unroll
          for (int ct = 0; ct < 2; ++ct) {
            int row = ct * 32 + q;
            bf16x8 ag = *(const bf16x8*)(ldsb + row * 64 +
                                         (((16 * sread) ^ ((row & 7) << 4)) >> 1));
            if (ct == 0) { oaccA0 = mfma16b(ag, pfA.h, oaccA0); oaccB0 = mfma16b(ag, pfB.h, oaccB0); }
            else         { oaccA1 = mfma16b(ag, pfA.h, oaccA1); oaccB1 = mfma16b(ag, pfB.h, oaccB1); }
          }
          __builtin_amdgcn_s_setprio(0);
        }
      }
    }
    if (step + 1 < NSTEP) { __syncthreads(); cur ^= 1; }  // uniform condition
  }
  // ---- epilogue: per group, chunk-total l + normalized f16 partial o ----
  lsumA += __shfl_xor(lsumA, 32);
  lsumB += __shfl_xor(lsumB, 32);
  float rlA = 1.0f / lsumA, rlB = 1.0f / lsumB;
  if (!hi) {
    part_l[(size_t)kc * BN + qrowA] = lsumA;
    part_l[(size_t)kc * BN + qrowB] = lsumB;
  }
  _Float16* poA = part_o + (((size_t)(kc * 2 + b) * NPIX) + qg0 + q) * 64;
  _Float16* poB = poA + (size_t)32 * 64;
#pragma unroll
  for (int ct = 0; ct < 2; ++ct) {
#pragma unroll
    for (int cg = 0; cg < 4; ++cg) {
      float a0 = (ct ? oaccA1[4 * cg + 0] : oaccA0[4 * cg + 0]) * rlA;
      float a1 = (ct ? oaccA1[4 * cg + 1] : oaccA0[4 * cg + 1]) * rlA;
      float a2 = (ct ? oaccA1[4 * cg + 2] : oaccA0[4 * cg + 2]) * rlA;
      float a3 = (ct ? oaccA1[4 * cg + 3] : oaccA0[4 * cg + 3]) * rlA;
      uint2v u;
      u[0] = __builtin_bit_cast(unsigned, __builtin_amdgcn_cvt_pkrtz(a0, a1));
      u[1] = __builtin_bit_cast(unsigned, __builtin_amdgcn_cvt_pkrtz(a2, a3));
      *(uint2v*)(poA + 32 * ct + 8 * cg + 4 * hi) = u;
      float b0 = (ct ? oaccB1[4 * cg + 0] : oaccB0[4 * cg + 0]) * rlB;
      float b1 = (ct ? oaccB1[4 * cg + 1] : oaccB0[4 * cg + 1]) * rlB;
      float b2 = (ct ? oaccB1[4 * cg + 2] : oaccB0[4 * cg + 2]) * rlB;
      float b3 = (ct ? oaccB1[4 * cg + 3] : oaccB0[4 * cg + 3]) * rlB;
      uint2v v;
      v[0] = __builtin_bit_cast(unsigned, __builtin_amdgcn_cvt_pkrtz(b0, b1));
      v[1] = __builtin_bit_cast(unsigned, __builtin_amdgcn_cvt_pkrtz(b2, b3));
      *(uint2v*)(poB + 32 * ct + 8 * cg + 4 * hi) = v;
    }
  }
}

// ---- K3: l-weighted combine + residual epilogue ----
__global__ __launch_bounds__(256) void reduce_kernel(
    const float* __restrict__ part_l, const _Float16* __restrict__ part_o,
    const float* __restrict__ x, const float* __restrict__ sig,
    float* __restrict__ out) {
  int t = threadIdx.x;
  int cg = t >> 6;                       // 0..3 -> channels cg*16..+15
  int qi = blockIdx.x * 64 + (t & 63);
  int b = qi >> 14, n = qi & (NPIX - 1);
  float lv[KSPLIT], L = 0.f;
#pragma unroll
  for (int kc = 0; kc < KSPLIT; kc++) {
    lv[kc] = part_l[(size_t)kc * BN + qi];
    L += lv[kc];
  }
  float o16[16];
#pragma unroll
  for (int j = 0; j < 16; j++) o16[j] = 0.f;
#pragma unroll
  for (int kc = 0; kc < KSPLIT; kc++) {
    const _Float16* po = part_o + (((size_t)(kc * 2 + b) * NPIX) + n) * 64 + cg * 16;
    f16x8 v0 = *(const f16x8*)po;
    f16x8 v1 = *(const f16x8*)(po + 8);
    float wv = lv[kc];
#pragma unroll
    for (int j = 0; j < 8; j++) {
      o16[j]     += wv * (float)v0[j];
      o16[8 + j] += wv * (float)v1[j];
    }
  }
  float scale = sig[0] / L;
#pragma unroll
  for (int j = 0; j < 16; j++) {
    int c = cg * 16 + j;
    size_t idx = ((size_t)b * 64 + c) * NPIX + n;
    out[idx] = x[idx] + scale * o16[j];
  }
}

extern "C" void kernel_launch(void* const* d_in, const int* in_sizes, int n_in,
                              void* d_out, int out_size, void* d_ws, size_t ws_size,
                              hipStream_t stream) {
  const float* x       = (const float*)d_in[0];
  const float* w_theta = (const float*)d_in[1];
  const float* b_theta = (const float*)d_in[2];
  const float* w_phi   = (const float*)d_in[3];
  const float* b_phi   = (const float*)d_in[4];
  const float* w_g     = (const float*)d_in[5];
  const float* b_g     = (const float*)d_in[6];
  const float* sigma   = (const float*)d_in[7];
  float* out = (float*)d_out;

  // Workspace layout (bytes):
  //   qf     @ 0        : BN*8*2              = 524288
  //   phiT   @ 524288   : 2*NPOOL*8*2         = 131072
  //   gT     @ 655360   : 2*64*NPOOL*2        = 1048576  (bf16)
  //   part_l @ 1703936  : KSPLIT*BN*4         = 1048576
  //   part_o @ 2752512  : KSPLIT*2*NPIX*64*2  = 33554432   (total ~36.3 MB)
  char* ws = (char*)d_ws;
  _Float16* qf     = (_Float16*)ws;
  _Float16* phiT   = (_Float16*)(ws + 524288);
  __bf16*   gT     = (__bf16*)(ws + 655360);
  float*    part_l = (float*)(ws + 1703936);
  _Float16* part_o = (_Float16*)(ws + 2752512);

  prep_kernel<<<256, 256, 0, stream>>>(x, w_theta, b_theta, w_phi, b_phi,
                                       w_g, b_g, qf, phiT, gT);
  attn_kernel<<<2 * 64 * KSPLIT, 256, 0, stream>>>(qf, phiT, gT,
                                                   part_l, part_o);
  reduce_kernel<<<512, 256, 0, stream>>>(part_l, part_o, x, sigma, out);
}